// Round 1
// baseline (628.723 us; speedup 1.0000x reference)
//
#include <hip/hip_runtime.h>
#include <stdint.h>

typedef unsigned long long ull;

#define TT 2048
#define NBATCH 64
#define NCHUNK 64   // 64 chunks of 32 slots

// ---------------- compile-time threefry2x32 (JAX semantics) ----------------
struct TF2 { uint32_t x, y; };

constexpr TF2 tf2x32(uint32_t k0, uint32_t k1, uint32_t x0, uint32_t x1) {
  uint32_t ks2 = k0 ^ k1 ^ 0x1BD11BDAu;
  x0 += k0; x1 += k1;
#define TFR_(r) x0 += x1; x1 = __builtin_rotateleft32(x1, r); x1 ^= x0;
  TFR_(13) TFR_(15) TFR_(26) TFR_(6)
  x0 += k1;  x1 += ks2 + 1u;
  TFR_(17) TFR_(29) TFR_(16) TFR_(24)
  x0 += ks2; x1 += k0 + 2u;
  TFR_(13) TFR_(15) TFR_(26) TFR_(6)
  x0 += k0;  x1 += k1 + 3u;
  TFR_(17) TFR_(29) TFR_(16) TFR_(24)
  x0 += k1;  x1 += ks2 + 4u;
  TFR_(13) TFR_(15) TFR_(26) TFR_(6)
  x0 += ks2; x1 += k0 + 5u;
#undef TFR_
  return {x0, x1};
}

// jax.random.split chain with threefry_partitionable=True:
//   new_key = TF(key, (0,0)); sub = TF(key, (0,1))
// Split into two constexpr halves to stay under the constexpr-step limit.
struct Half_ { uint32_t a[1024]; uint32_t b[1024]; uint32_t k0, k1; };

constexpr Half_ make_half(uint32_t k0, uint32_t k1) {
  Half_ h{};
  for (int t = 0; t < 1024; ++t) {
    TF2 nk = tf2x32(k0, k1, 0u, 0u);
    TF2 sb = tf2x32(k0, k1, 0u, 1u);
    h.a[t] = sb.x; h.b[t] = sb.y;
    k0 = nk.x; k1 = nk.y;
  }
  h.k0 = k0; h.k1 = k1;
  return h;
}

namespace ckeys {
constexpr Half_ H0 = make_half(0u, 42u);      // jax.random.key(42) -> (0,42)
constexpr Half_ H1 = make_half(H0.k0, H0.k1);
}
__constant__ Half_ dH0 = ckeys::H0;
__constant__ Half_ dH1 = ckeys::H1;

// ---------------- XLA fast-tanh replica (f32 rational, fmaf) ----------------
__device__ __forceinline__ float tanh_xla(float x) {
#pragma clang fp contract(off)
  float ax = fabsf(x);
  float xc = fminf(fmaxf(x, -7.90531110763549805f), 7.90531110763549805f);
  float x2 = xc * xc;
  float p = fmaf(x2, -2.76076847742355e-16f, 2.00018790482477e-13f);
  p = fmaf(x2, p, -8.60467152213735e-11f);
  p = fmaf(x2, p, 5.12229709037114e-08f);
  p = fmaf(x2, p, 1.48572235717979e-05f);
  p = fmaf(x2, p, 6.37261928875436e-04f);
  p = fmaf(x2, p, 4.89352455891786e-03f);
  p = xc * p;
  float q = fmaf(x2, 1.19825839466702e-06f, 1.18534705686654e-04f);
  q = fmaf(x2, q, 2.26843463243900e-03f);
  q = fmaf(x2, q, 4.89352518554385e-03f);
  return (ax < 0.0004f) ? x : (p / q);
}

// sigmoid replica: f32 ops, exp done in f64 (~correctly rounded expf)
__device__ __forceinline__ float sig_ref(float z) {
#pragma clang fp contract(off)
  float e = (float)exp(-(double)z);
  return 1.0f / (1.0f + e);
}

// ordered-int encode/decode for monotone binary search over floats
__device__ __forceinline__ uint32_t ford(float f) {
  uint32_t x = __float_as_uint(f);
  return (x & 0x80000000u) ? ~x : (x | 0x80000000u);
}
__device__ __forceinline__ float fdec(uint32_t k) {
  uint32_t b = (k & 0x80000000u) ? (k & 0x7fffffffu) : ~k;
  return __uint_as_float(b);
}

// tau = max f32 z with sig_ref(z) <= u   (spike <=> z > tau, exactly u < sig(z))
__device__ float find_tau(float u) {
  uint32_t klo = ford(-95.0f), khi = ford(95.0f);
  while (khi - klo > 1u) {
    uint32_t km = klo + ((khi - klo) >> 1);
    float zm = fdec(km);
    if (sig_ref(zm) <= u) klo = km; else khi = km;
  }
  return fdec(klo);
}

// ---------------- pre kernel: nn, uniforms->tau, refract kernel, flags ----------------
__global__ void ap_pre_kernel(const float* __restrict__ V, const float* __restrict__ D,
                              const float* __restrict__ w1, const float* __restrict__ b1,
                              const float* __restrict__ w2, const float* __restrict__ b2,
                              const float* __restrict__ Wr,
                              float2* __restrict__ zbu, float* __restrict__ rk,
                              uint32_t* flags) {
#pragma clang fp contract(off)
  int tid = threadIdx.x;
  int blk = blockIdx.x;
  if (blk < 512) {
    int idx = blk * 256 + tid;          // idx = b*2048 + t
    int b = idx >> 11, t = idx & 2047;
    float v = V[idx], dd = D[idx];
    // pointwise MLP (Eigen-gemm style fma chains)
    float acc = 0.f;
#pragma unroll
    for (int h = 0; h < 5; ++h) {
      float m = fmaf(w1[2 * h + 1], dd, w1[2 * h] * v) + b1[h];
      float th = tanh_xla(m);
      acc = (h == 0) ? (w2[0] * th) : fmaf(w2[h], th, acc);
    }
    float z0 = acc + b2[0];
    // uniform (partitionable random_bits: counter (0,b), bits = y0^y1)
    uint32_t ka = (t < 1024) ? dH0.a[t] : dH1.a[t - 1024];
    uint32_t kb = (t < 1024) ? dH0.b[t] : dH1.b[t - 1024];
    TF2 o = tf2x32(ka, kb, 0u, (uint32_t)b);
    uint32_t bits = o.x ^ o.y;
    float u = __uint_as_float((bits >> 9) | 0x3f800000u) - 1.0f;
    float tau = find_tau(u);
    zbu[t * 64 + b] = make_float2(z0, tau);
  } else if (blk < 514) {
    int d = (blk - 512) * 256 + tid;    // 0..511 ; rk[d] for lag d (1..501), else 0
    float val = 0.f;
    if (d >= 1 && d <= 501) {
      double raw = 7.5 * log((double)(d - 1) + 1.0 + 1e-7);
      float a = 0.f;
      for (int i = 0; i < 30; ++i) {
        double phi = (0.5 * 3.141592653589793) * (double)i;
        float bf;
        if (raw < phi - 3.141592653589793 || raw > phi + 3.141592653589793) bf = 0.f;
        else bf = (float)(0.5 * cos(raw - phi) + 0.5);
        a = fmaf(Wr[i], bf, a);
      }
      val = a;
    }
    rk[d] = val;
  } else {
    if (tid == 0) flags[0] = 0u;                       // chunks_done
    if (tid >= 1 && tid <= NCHUNK) {
      int kk = tid - 1;
      flags[1 + kk] = (kk <= 3) ? 2u : 0u;             // conv_done (chunks 0..3 trivially done)
    }
  }
}

// ---------------- main kernel: block0 = serial wave, blocks 1..120 = conv ----------------
__global__ void __launch_bounds__(512, 1)
ap_main_kernel(float2* zbu, const float* __restrict__ rk,
               float* __restrict__ zarr, ull* sw, uint32_t* flags) {
  __shared__ float lutS[16][256];     // octet o: lags 3+8o .. 10+8o
  __shared__ ull swL[416];
  __shared__ float rkL[512];
  __shared__ uint32_t colb[32][13];

  int tid = threadIdx.x;

  if (blockIdx.x == 0) {
    // ---- prologue: LUT build (all waves) ----
    for (int e = tid; e < 16 * 256; e += 512) {
      int o = e >> 8, vb = e & 255;
      float s = 0.f;
      for (int i = 0; i < 8; ++i)
        if (vb & (1 << i)) s += rk[3 + 8 * o + i];
      lutS[o][vb] = s;
    }
    __syncthreads();
    if (tid >= 64) return;            // only wave 0 continues
    int lane = tid;                   // lane = batch row b
    float rk1 = rk[1], rk2 = rk[2];
    float2 pf[4];
#pragma unroll
    for (int q = 0; q < 4; ++q) pf[q] = zbu[q * 64 + lane];
    uint32_t m0 = 0, m1 = 0, m2 = 0, m3 = 0, s1u = 0;
    float s1f = 0.f, s2f = 0.f;
    float l_0=0,l_1=0,l_2=0,l_3=0,l_4=0,l_5=0,l_6=0,l_7=0,
          l_8=0,l_9=0,l_10=0,l_11=0,l_12=0,l_13=0,l_14=0,l_15=0;

    auto body = [&](int tt, float2& PF) {
      if ((tt & 31) == 0) {
        int kk = tt >> 5;
        if (kk > 0 && lane == 0)
          __hip_atomic_store(&flags[0], (uint32_t)kk, __ATOMIC_RELEASE,
                             __HIP_MEMORY_SCOPE_AGENT);
      } else if ((tt & 31) == 16) {
        int k1 = (tt >> 5) + 1;
        if (k1 < NCHUNK) {
          while (__hip_atomic_load(&flags[1 + k1], __ATOMIC_ACQUIRE,
                                   __HIP_MEMORY_SCOPE_AGENT) < 2u)
            __builtin_amdgcn_s_sleep(2);
        }
      }
      // issue LUT reads for slot tt+1 (mask bit j = spike_{tt-2-j}; lag = 3+8o+i)
      float n_0  = lutS[0 ][(m0      ) & 255u];
      float n_1  = lutS[1 ][(m0 >>  8) & 255u];
      float n_2  = lutS[2 ][(m0 >> 16) & 255u];
      float n_3  = lutS[3 ][(m0 >> 24) & 255u];
      float n_4  = lutS[4 ][(m1      ) & 255u];
      float n_5  = lutS[5 ][(m1 >>  8) & 255u];
      float n_6  = lutS[6 ][(m1 >> 16) & 255u];
      float n_7  = lutS[7 ][(m1 >> 24) & 255u];
      float n_8  = lutS[8 ][(m2      ) & 255u];
      float n_9  = lutS[9 ][(m2 >>  8) & 255u];
      float n_10 = lutS[10][(m2 >> 16) & 255u];
      float n_11 = lutS[11][(m2 >> 24) & 255u];
      float n_12 = lutS[12][(m3      ) & 255u];
      float n_13 = lutS[13][(m3 >>  8) & 255u];
      float n_14 = lutS[14][(m3 >> 16) & 255u];
      float n_15 = lutS[15][(m3 >> 24) & 255u];
      // gather value for THIS slot (reads issued last iteration)
      float g = (((l_0 + l_1) + (l_2 + l_3)) + ((l_4 + l_5) + (l_6 + l_7)))
              + (((l_8 + l_9) + (l_10 + l_11)) + ((l_12 + l_13) + (l_14 + l_15)));
      float z = PF.x + g;               // PF.x = nn + conv baseline (lags >=131)
      z = fmaf(rk2, s2f, z);
      z = fmaf(rk1, s1f, z);
      bool sp = (z > PF.y);             // exactly u < sigmoid(z)
      zarr[tt * 64 + lane] = z;
      ull bal = __ballot(sp);
      if (lane == 0) sw[tt] = bal;
      // prefetch zbu for slot tt+4
      int tn = tt + 4; if (tn > 2047) tn = 2047;
      PF = zbu[tn * 64 + lane];
      // shift mask, insert spike_{tt-1}
      m3 = (m3 << 1) | (m2 >> 31);
      m2 = (m2 << 1) | (m1 >> 31);
      m1 = (m1 << 1) | (m0 >> 31);
      m0 = (m0 << 1) | s1u;
      s2f = s1f;
      s1f = sp ? 1.0f : 0.0f;
      s1u = sp ? 1u : 0u;
      l_0=n_0; l_1=n_1; l_2=n_2; l_3=n_3; l_4=n_4; l_5=n_5; l_6=n_6; l_7=n_7;
      l_8=n_8; l_9=n_9; l_10=n_10; l_11=n_11; l_12=n_12; l_13=n_13; l_14=n_14; l_15=n_15;
    };

    for (int t = 0; t < TT; t += 4) {
#pragma unroll
      for (int q = 0; q < 4; ++q) body(t + q, pf[q]);
    }
    return;
  }

  // ---- conv blocks: baseline for lags 131..501, chunk k, half h ----
  int c = (int)blockIdx.x - 1;
  int k = 4 + (c >> 1), h = c & 1;
  if (tid == 0) {
    while ((int)__hip_atomic_load(&flags[0], __ATOMIC_ACQUIRE,
                                  __HIP_MEMORY_SCOPE_AGENT) < k - 3)
      __builtin_amdgcn_s_sleep(8);
  }
  __syncthreads();
  int s0 = 32 * k - 501;
  for (int i = tid; i < 416; i += 512) {
    int s = s0 + i;
    swL[i] = (s >= 0 && i < 403) ? sw[s] : 0ull;
  }
  rkL[tid] = rk[tid];
  if (tid < 512 - 512) {}   // (512 threads cover rk exactly)
  __syncthreads();
  if (tid < 416) {
    int bl = tid & 31, ww = tid >> 5;
    int b = 32 * h + bl;
    uint32_t word = 0;
    for (int j = 0; j < 32; ++j)
      word |= (uint32_t)((swL[32 * ww + j] >> b) & 1ull) << j;
    colb[bl][ww] = word;
  }
  __syncthreads();
  {
    int bl = tid & 31;
    int b = 32 * h + bl;
    int t0 = tid >> 5;                  // 0..15
    uint32_t cw[13];
#pragma unroll
    for (int ww = 0; ww < 13; ++ww) cw[ww] = colb[bl][ww];
#pragma unroll 1
    for (int cc = 0; cc < 2; ++cc) {
      int th = t0 + 16 * cc;
      int t = 32 * k + th;
      float acc = 0.f;
#pragma unroll
      for (int ww = 0; ww < 12; ++ww) {
        uint32_t al = (uint32_t)((((uint64_t)cw[ww + 1] << 32) | (uint64_t)cw[ww]) >> th);
        int imax = (ww == 11) ? 19 : 32;   // lags 131..501
#pragma unroll 4
        for (int i = 0; i < imax; ++i) {
          float bv = (float)((al >> i) & 1u);
          acc = fmaf(bv, rkL[501 - (32 * ww + i)], acc);
        }
      }
      zbu[t * 64 + b].x += acc;
    }
  }
  __syncthreads();
  if (tid == 0)
    __hip_atomic_fetch_add(&flags[1 + k], 1u, __ATOMIC_RELEASE,
                           __HIP_MEMORY_SCOPE_AGENT);
}

// ---------------- post kernel: emit S and P ----------------
__global__ void ap_post_kernel(const float* __restrict__ zarr, const ull* __restrict__ sw,
                               float* __restrict__ out) {
#pragma clang fp contract(off)
  int idx = blockIdx.x * 256 + threadIdx.x;   // b*2048 + t
  int b = idx >> 11, t = idx & 2047;
  float z = zarr[t * 64 + b];
  float S = (float)((sw[t] >> b) & 1ull);
  float e = (float)exp(-(double)z);
  float P = 1.0f / (1.0f + e);
  out[idx] = S;
  out[131072 + idx] = P;
}

extern "C" void kernel_launch(void* const* d_in, const int* in_sizes, int n_in,
                              void* d_out, int out_size, void* d_ws, size_t ws_size,
                              hipStream_t stream) {
  (void)in_sizes; (void)n_in; (void)out_size; (void)ws_size;
  const float* V  = (const float*)d_in[0];
  const float* D  = (const float*)d_in[1];
  const float* w1 = (const float*)d_in[2];
  const float* b1 = (const float*)d_in[3];
  const float* w2 = (const float*)d_in[4];
  const float* b2 = (const float*)d_in[5];
  const float* Wr = (const float*)d_in[6];

  char* w = (char*)d_ws;                       // ~1.6 MB of ws used
  float2*   zbu   = (float2*)w;                // [2048*64] (z_base, tau)
  float*    zarr  = (float*)(w + 0x100000);    // [2048*64]
  ull*      swp   = (ull*)(w + 0x180000);      // [2048] spike ballots
  float*    rk    = (float*)(w + 0x184000);    // [512]
  uint32_t* flags = (uint32_t*)(w + 0x184800); // [65]

  ap_pre_kernel<<<515, 256, 0, stream>>>(V, D, w1, b1, w2, b2, Wr, zbu, rk, flags);
  ap_main_kernel<<<121, 512, 0, stream>>>(zbu, rk, zarr, swp, flags);
  ap_post_kernel<<<512, 256, 0, stream>>>(zarr, swp, (float*)d_out);
}